// Round 1
// baseline (434.140 us; speedup 1.0000x reference)
//
#include <hip/hip_runtime.h>

// LIF activation: Vm_{t+1} = relu(x_t + (1-w_leak)*Vm_t*[Vm_t<1]), spike = [Vm>1]
// [B,T,C] = [128,1000,512] fp32. One thread per (b,c) chain, sequential over t.
// Coalescing: lane i -> c=base+i, so each timestep is a contiguous 256B/wave access.
// Double-buffered U=10 chunks keep 10-20 loads in flight per wave (only 1 wave/SIMD
// at this thread count, so per-wave MLP is what hides the ~900cyc HBM latency).

constexpr int Bn  = 128;
constexpr int Tn  = 1000;
constexpr int Cn  = 512;
constexpr int U   = 10;        // timesteps per chunk
constexpr int NCH = Tn / U;    // 100 chunks (even -> clean 2x unroll)

__global__ __launch_bounds__(256) void lif_kernel(const float* __restrict__ x,
                                                  const float* __restrict__ w_leak,
                                                  float* __restrict__ out) {
    const int gid = blockIdx.x * 256 + threadIdx.x;   // 0..65535
    const int c   = gid & (Cn - 1);
    const int b   = gid >> 9;                          // /512
    const float oml = 1.0f - w_leak[c];                // matches np: (1.0 - w_leak) in fp32

    const size_t base = (size_t)b * Tn * Cn + c;
    const float* xp = x + base;
    float*       op = out + base;

    float Vm = 0.0f;
    float bufA[U], bufB[U];

    // prologue: prefetch chunk 0
#pragma unroll
    for (int i = 0; i < U; ++i) bufA[i] = xp[i * Cn];

    for (int ch = 0; ch < NCH; ch += 2) {
        // prefetch chunk ch+1 -> bufB (overlaps with compute of bufA)
        {
            const float* xn = xp + (size_t)(ch + 1) * U * Cn;
#pragma unroll
            for (int i = 0; i < U; ++i) bufB[i] = xn[i * Cn];
        }
        // compute + store chunk ch from bufA
        {
            float* on = op + (size_t)ch * U * Cn;
#pragma unroll
            for (int i = 0; i < U; ++i) {
                float prod = oml * Vm;                 // round(oml*Vm) — separate mul, matches ref
                prod = (Vm < 1.0f) ? prod : 0.0f;      // keep-gate: exact select (== *keep)
                float v = bufA[i] + prod;              // round(x + prod)
                Vm = fmaxf(v, 0.0f);                   // relu
                on[i * Cn] = (Vm > 1.0f) ? 1.0f : 0.0f; // spike(Vm - 1) — sign-exact
            }
        }
        // prefetch chunk ch+2 -> bufA
        if (ch + 2 < NCH) {
            const float* xn = xp + (size_t)(ch + 2) * U * Cn;
#pragma unroll
            for (int i = 0; i < U; ++i) bufA[i] = xn[i * Cn];
        }
        // compute + store chunk ch+1 from bufB
        {
            float* on = op + (size_t)(ch + 1) * U * Cn;
#pragma unroll
            for (int i = 0; i < U; ++i) {
                float prod = oml * Vm;
                prod = (Vm < 1.0f) ? prod : 0.0f;
                float v = bufB[i] + prod;
                Vm = fmaxf(v, 0.0f);
                on[i * Cn] = (Vm > 1.0f) ? 1.0f : 0.0f;
            }
        }
    }
}

extern "C" void kernel_launch(void* const* d_in, const int* in_sizes, int n_in,
                              void* d_out, int out_size, void* d_ws, size_t ws_size,
                              hipStream_t stream) {
    const float* x      = (const float*)d_in[0];
    const float* w_leak = (const float*)d_in[1];
    float*       out    = (float*)d_out;

    const int total  = Bn * Cn;        // 65536 threads
    const int block  = 256;
    const int grid   = total / block;  // 256 blocks -> 1 per CU
    lif_kernel<<<grid, block, 0, stream>>>(x, w_leak, out);
}

// Round 2
// 433.852 us; speedup vs baseline: 1.0007x; 1.0007x over previous
//
#include <hip/hip_runtime.h>

// LIF activation: Vm_{t+1} = relu(x_t + (1-w_leak)*Vm_t*[Vm_t<1]), spike = [Vm>1]
// [B,T,C] = [128,1000,512] fp32. One thread per (b,c) chain, sequential over t.
// Lane i -> c = base+i: every per-timestep access is a contiguous 256B/wave txn.
//
// R1 -> R2: 434us = ~1 full HBM latency per timestep => the machine scheduler
// was sinking the prefetch loads to their uses (no MLP). Pin the pipeline with
// sched_barrier(0) fences around each phase, and deepen to U=20 (5KB/wave in
// flight; ~20KB/CU > ~9KB needed for 6.3TB/s at ~900cyc latency).

constexpr int Bn  = 128;
constexpr int Tn  = 1000;
constexpr int Cn  = 512;
constexpr int U   = 20;        // timesteps per chunk
constexpr int NCH = Tn / U;    // 50 chunks (even -> clean 2x unroll)

__global__ __launch_bounds__(256) void lif_kernel(const float* __restrict__ x,
                                                  const float* __restrict__ w_leak,
                                                  float* __restrict__ out) {
    const int gid = blockIdx.x * 256 + threadIdx.x;   // 0..65535
    const int c   = gid & (Cn - 1);
    const int b   = gid >> 9;                          // /512
    const float oml = 1.0f - w_leak[c];                // matches np: (1.0 - w_leak) in fp32

    const size_t base = (size_t)b * Tn * Cn + c;
    const float* xp = x + base;
    float*       op = out + base;

    float Vm = 0.0f;
    float bufA[U], bufB[U];

    // prologue: prefetch chunk 0
#pragma unroll
    for (int i = 0; i < U; ++i) bufA[i] = xp[i * Cn];
    __builtin_amdgcn_sched_barrier(0);   // loads above may not sink below

    for (int ch = 0; ch < NCH; ch += 2) {
        // prefetch chunk ch+1 -> bufB (overlaps with compute of bufA)
        {
            const float* xn = xp + (size_t)(ch + 1) * U * Cn;
#pragma unroll
            for (int i = 0; i < U; ++i) bufB[i] = xn[i * Cn];
        }
        __builtin_amdgcn_sched_barrier(0);
        // compute + store chunk ch from bufA
        {
            float* on = op + (size_t)ch * U * Cn;
#pragma unroll
            for (int i = 0; i < U; ++i) {
                float prod = oml * Vm;                 // round(oml*Vm) — separate mul, matches ref
                prod = (Vm < 1.0f) ? prod : 0.0f;      // keep-gate: exact select (== *keep)
                float v = bufA[i] + prod;              // round(x + prod)
                Vm = fmaxf(v, 0.0f);                   // relu
                on[i * Cn] = (Vm > 1.0f) ? 1.0f : 0.0f; // spike(Vm - 1) — sign-exact
            }
        }
        __builtin_amdgcn_sched_barrier(0);
        // prefetch chunk ch+2 -> bufA
        if (ch + 2 < NCH) {
            const float* xn = xp + (size_t)(ch + 2) * U * Cn;
#pragma unroll
            for (int i = 0; i < U; ++i) bufA[i] = xn[i * Cn];
        }
        __builtin_amdgcn_sched_barrier(0);
        // compute + store chunk ch+1 from bufB
        {
            float* on = op + (size_t)(ch + 1) * U * Cn;
#pragma unroll
            for (int i = 0; i < U; ++i) {
                float prod = oml * Vm;
                prod = (Vm < 1.0f) ? prod : 0.0f;
                float v = bufB[i] + prod;
                Vm = fmaxf(v, 0.0f);
                on[i * Cn] = (Vm > 1.0f) ? 1.0f : 0.0f;
            }
        }
        __builtin_amdgcn_sched_barrier(0);
    }
}

extern "C" void kernel_launch(void* const* d_in, const int* in_sizes, int n_in,
                              void* d_out, int out_size, void* d_ws, size_t ws_size,
                              hipStream_t stream) {
    const float* x      = (const float*)d_in[0];
    const float* w_leak = (const float*)d_in[1];
    float*       out    = (float*)d_out;

    const int total  = Bn * Cn;        // 65536 threads
    const int block  = 256;
    const int grid   = total / block;  // 256 blocks -> 1 per CU
    lif_kernel<<<grid, block, 0, stream>>>(x, w_leak, out);
}